// Round 6
// baseline (497.745 us; speedup 1.0000x reference)
//
#include <hip/hip_runtime.h>
#include <math.h>

#define NB 4
#define NN 1024
#define NM 1024
#define NC 384
#define NK 10
#define NG 2
#define NGC 192
#define NH 6

#define GSZ ((size_t)NB * NM * NC)   // per-g table size (elements)
#define QSZ ((size_t)NB * NN * NC)
#define NCNC ((size_t)NC * NC)

// Wt_all layout (floats)
#define OFF_WQ 0
#define OFF_W1B 147456
#define OFF_WK0 221184
#define OFF_WK1 294912
#define OFF_WV0 368640
#define OFF_WV1 442368
#define OFF_WPROJ 516096
#define WT_ALL_FLOATS 663552

__device__ __forceinline__ float wred_sum(float v) {
#pragma unroll
  for (int m = 32; m >= 1; m >>= 1) v += __shfl_xor(v, m, 64);
  return v;
}

// lexicographic (d, m) min across 64 lanes; ties -> lower m (matches top_k)
__device__ __forceinline__ void wred_argmin(float& d, int& m) {
#pragma unroll
  for (int off = 32; off >= 1; off >>= 1) {
    float od = __shfl_xor(d, off, 64);
    int om = __shfl_xor(m, off, 64);
    if (od < d || (od == d && om < m)) { d = od; m = om; }
  }
}

__device__ __forceinline__ ushort f2bf(float x) {  // RNE, finite inputs
  unsigned u = __float_as_uint(x);
  unsigned r = (u + 0x7fffu + ((u >> 16) & 1u)) >> 16;
  return (ushort)r;
}
__device__ __forceinline__ float b2f(ushort s) {
  return __uint_as_float(((unsigned)s) << 16);
}

// all 7 weight transposes in one launch; blockIdx.y = job
__global__ void transpose_all_k(const float* __restrict__ Wq, const float* __restrict__ Woff1,
                                const float* __restrict__ Wk, const float* __restrict__ Wv,
                                const float* __restrict__ Wproj, float* __restrict__ Wt_all) {
  const float* W;
  int i0, icount, doff;
  switch (blockIdx.y) {
    case 0: W = Wq;    i0 = 0;   icount = NC;  doff = OFF_WQ;    break;
    case 1: W = Woff1; i0 = NGC; icount = NGC; doff = OFF_W1B;   break;
    case 2: W = Wk;    i0 = 0;   icount = NGC; doff = OFF_WK0;   break;
    case 3: W = Wk;    i0 = NGC; icount = NGC; doff = OFF_WK1;   break;
    case 4: W = Wv;    i0 = 0;   icount = NGC; doff = OFF_WV0;   break;
    case 5: W = Wv;    i0 = NGC; icount = NGC; doff = OFF_WV1;   break;
    default: W = Wproj; i0 = 0;  icount = NC;  doff = OFF_WPROJ; break;
  }
  int id = blockIdx.x * 256 + threadIdx.x;
  if (id >= icount * NC) return;
  int o = id % NC;
  int i = id / NC;
  Wt_all[doff + (size_t)i * NC + o] = W[(size_t)o * NC + i0 + i];
}

// WcombAll[job][i][o], job = kind*2+g:
//   kind 0 (Wvoff): Σ_j Woff1[o][j]       * Wvoff[g*192+j][i]   (vcontrib weights)
//   kind 1 (Wq)   : Σ_j Woff1[o][192+j]   * Wq   [g*192+j][i]   (qcontrib weights)
__global__ __launch_bounds__(256) void wcomb2_k(const float* __restrict__ Woff1,
                                                const float* __restrict__ Wvoff,
                                                const float* __restrict__ Wq,
                                                float* __restrict__ WcombAll) {
  int o = blockIdx.x;
  int job = blockIdx.y;
  int g = job & 1, kind = job >> 1;
  const float* Wsrc = kind ? Wq : Wvoff;
  __shared__ float w1[NGC];
  for (int j = threadIdx.x; j < NGC; j += 256) w1[j] = Woff1[(size_t)o * NC + kind * NGC + j];
  __syncthreads();
  for (int i = threadIdx.x; i < NC; i += 256) {
    float acc = 0.f;
#pragma unroll 4
    for (int j = 0; j < NGC; ++j)
      acc = fmaf(w1[j], Wsrc[(size_t)(g * NGC + j) * NC + i], acc);
    WcombAll[((size_t)job * NC + i) * NC + o] = acc;
  }
}

// generic 16-row 4x4 register-blocked GEMM (used for out-projection)
__global__ __launch_bounds__(384) void gemm16_k(const float* __restrict__ X, int IN, int xoff0,
                                                int xoff_stride, const float* __restrict__ Wt0,
                                                size_t wstride, const float* __restrict__ bias,
                                                float* __restrict__ Y0, size_t ystride) {
  __shared__ __align__(16) float xs[NC][20];
  int tid = threadIdx.x;
  int og = tid % 96, rg = tid / 96;
  int r0 = blockIdx.x * 16;
  int job = blockIdx.y;
  int xoff = xoff0 + job * xoff_stride;
  const float* Wt = Wt0 + (size_t)job * wstride;
  float* Y = Y0 + (size_t)job * ystride;
  for (int t = tid; t < 16 * IN; t += 384) {
    int r = t / IN, kk = t % IN;
    xs[kk][r] = X[(size_t)(r0 + r) * NC + xoff + kk];
  }
  __syncthreads();
  float acc[4][4];
#pragma unroll
  for (int i = 0; i < 4; ++i)
#pragma unroll
    for (int j = 0; j < 4; ++j) acc[i][j] = 0.f;
  int o = og * 4;
#pragma unroll 4
  for (int kk = 0; kk < IN; ++kk) {
    float4 w4 = *(const float4*)&Wt[(size_t)kk * NC + o];
    float4 x4 = *(const float4*)&xs[kk][rg * 4];
    float xr[4] = {x4.x, x4.y, x4.z, x4.w};
    float wr[4] = {w4.x, w4.y, w4.z, w4.w};
#pragma unroll
    for (int ri = 0; ri < 4; ++ri)
#pragma unroll
      for (int oi = 0; oi < 4; ++oi) acc[ri][oi] = fmaf(xr[ri], wr[oi], acc[ri][oi]);
  }
  float4 bv = make_float4(0.f, 0.f, 0.f, 0.f);
  if (bias) bv = *(const float4*)&bias[o];
#pragma unroll
  for (int ri = 0; ri < 4; ++ri) {
    float4 ov;
    ov.x = acc[ri][0] + bv.x;
    ov.y = acc[ri][1] + bv.y;
    ov.z = acc[ri][2] + bv.z;
    ov.w = acc[ri][3] + bv.w;
    *(float4*)&Y[(size_t)(r0 + rg * 4 + ri) * NC + o] = ov;
  }
}

// all 9 projections in one launch; blockIdx.y = job:
//  0,1: vcontrib g0/g1 = v @ Wcomb[g]            (f32)
//  2,3: Kc g0/g1       = v_slice @ WkT[g]        (bf16)
//  4,5: Vc g0/g1       = v_slice @ WvT[g]        (bf16)
//  6  : qp             = q @ WqT                 (f32)
//  7,8: qcontrib g0/g1 = q @ Wqc[g]              (f32)
__global__ __launch_bounds__(384) void projall_k(const float* __restrict__ q,
                                                 const float* __restrict__ v,
                                                 const float* __restrict__ WcombAll,
                                                 const float* __restrict__ Wt_all,
                                                 float* __restrict__ qp,
                                                 float* __restrict__ qcontrib,
                                                 float* __restrict__ vcontrib,
                                                 ushort* __restrict__ KcT,
                                                 ushort* __restrict__ VcT) {
  __shared__ __align__(16) float xs[NC][20];
  int tid = threadIdx.x;
  int og = tid % 96, rg = tid / 96;
  int r0 = blockIdx.x * 16;
  int job = blockIdx.y;
  const float* X;
  const float* Wt;
  int IN, xoff;
  float* Yf = nullptr;
  ushort* Yh = nullptr;
  switch (job) {
    case 0: X = v; IN = NC;  xoff = 0;   Wt = WcombAll;            Yf = vcontrib;       break;
    case 1: X = v; IN = NC;  xoff = 0;   Wt = WcombAll + NCNC;     Yf = vcontrib + GSZ; break;
    case 2: X = v; IN = NGC; xoff = 0;   Wt = Wt_all + OFF_WK0;    Yh = KcT;            break;
    case 3: X = v; IN = NGC; xoff = NGC; Wt = Wt_all + OFF_WK1;    Yh = KcT + GSZ;      break;
    case 4: X = v; IN = NGC; xoff = 0;   Wt = Wt_all + OFF_WV0;    Yh = VcT;            break;
    case 5: X = v; IN = NGC; xoff = NGC; Wt = Wt_all + OFF_WV1;    Yh = VcT + GSZ;      break;
    case 6: X = q; IN = NC;  xoff = 0;   Wt = Wt_all + OFF_WQ;     Yf = qp;             break;
    case 7: X = q; IN = NC;  xoff = 0;   Wt = WcombAll + 2 * NCNC; Yf = qcontrib;       break;
    default:X = q; IN = NC;  xoff = 0;   Wt = WcombAll + 3 * NCNC; Yf = qcontrib + QSZ; break;
  }
  for (int t = tid; t < 16 * IN; t += 384) {
    int r = t / IN, kk = t % IN;
    xs[kk][r] = X[(size_t)(r0 + r) * NC + xoff + kk];
  }
  __syncthreads();
  float acc[4][4];
#pragma unroll
  for (int i = 0; i < 4; ++i)
#pragma unroll
    for (int j = 0; j < 4; ++j) acc[i][j] = 0.f;
  int o = og * 4;
#pragma unroll 4
  for (int kk = 0; kk < IN; ++kk) {
    float4 w4 = *(const float4*)&Wt[(size_t)kk * NC + o];
    float4 x4 = *(const float4*)&xs[kk][rg * 4];
    float xr[4] = {x4.x, x4.y, x4.z, x4.w};
    float wr[4] = {w4.x, w4.y, w4.z, w4.w};
#pragma unroll
    for (int ri = 0; ri < 4; ++ri)
#pragma unroll
      for (int oi = 0; oi < 4; ++oi) acc[ri][oi] = fmaf(xr[ri], wr[oi], acc[ri][oi]);
  }
  if (Yf) {
#pragma unroll
    for (int ri = 0; ri < 4; ++ri)
      *(float4*)&Yf[(size_t)(r0 + rg * 4 + ri) * NC + o] =
          make_float4(acc[ri][0], acc[ri][1], acc[ri][2], acc[ri][3]);
  } else {
#pragma unroll
    for (int ri = 0; ri < 4; ++ri) {
      ushort4 pk;
      pk.x = f2bf(acc[ri][0]);
      pk.y = f2bf(acc[ri][1]);
      pk.z = f2bf(acc[ri][2]);
      pk.w = f2bf(acc[ri][3]);
      *(ushort4*)&Yh[(size_t)(r0 + rg * 4 + ri) * NC + o] = pk;
    }
  }
}

// wave-per-query KNN: lane scans 16 candidates -> register top-10 -> argmin-merge
__global__ __launch_bounds__(256) void knn2_k(const float* __restrict__ q_pos,
                                              const float* __restrict__ v_pos,
                                              int* __restrict__ knn_idx) {
  __shared__ float4 cpos[NM];
  int tid = threadIdx.x, lane = tid & 63, wid = tid >> 6;
  int b = blockIdx.x / (NN / 4);
  int n = (blockIdx.x % (NN / 4)) * 4 + wid;
  for (int t = tid; t < NM; t += 256) {
    float x = v_pos[((size_t)b * NM + t) * 3 + 0];
    float y = v_pos[((size_t)b * NM + t) * 3 + 1];
    float z = v_pos[((size_t)b * NM + t) * 3 + 2];
    cpos[t] = make_float4(x, y, z, x * x + y * y + z * z);
  }
  __syncthreads();
  float qx = q_pos[((size_t)b * NN + n) * 3 + 0];
  float qy = q_pos[((size_t)b * NN + n) * 3 + 1];
  float qz = q_pos[((size_t)b * NN + n) * 3 + 2];
  float qq = qx * qx + qy * qy + qz * qz;
  float bd[NK];
  int bi[NK];
#pragma unroll
  for (int j = 0; j < NK; ++j) { bd[j] = 1e30f; bi[j] = 0x7fffffff; }
#pragma unroll
  for (int t = 0; t < NM / 64; ++t) {
    int m = t * 64 + lane;
    float4 cc = cpos[m];
    float d = qq + cc.w - 2.f * (qx * cc.x + qy * cc.y + qz * cc.z);
    if (d < bd[NK - 1]) {
#pragma unroll
      for (int j = NK - 1; j > 0; --j) {
        if (d < bd[j - 1]) { bd[j] = bd[j - 1]; bi[j] = bi[j - 1]; }
        else if (d < bd[j]) { bd[j] = d; bi[j] = m; }
      }
      if (d < bd[0]) { bd[0] = d; bi[0] = m; }
    }
  }
  size_t base = ((size_t)b * NN + n) * NK;
#pragma unroll
  for (int round = 0; round < NK; ++round) {
    float dh = bd[0];
    int mh = bi[0];
    wred_argmin(dh, mh);
    if (lane == 0) knn_idx[base + round] = mh;
    if (bi[0] == mh) {
#pragma unroll
      for (int j = 0; j < NK - 1; ++j) { bd[j] = bd[j + 1]; bi[j] = bi[j + 1]; }
      bd[NK - 1] = 1e30f; bi[NK - 1] = 0x7fffffff;
    }
  }
}

// fused MLP + three_nn: one wave per (b,g,n,k) row
__global__ __launch_bounds__(256) void mlp3nn_k(
    const float* __restrict__ vcontrib, const float* __restrict__ qcontrib,
    const float* __restrict__ boff1, const float* __restrict__ ln_g,
    const float* __restrict__ ln_b, const float* __restrict__ Woff2,
    const int* __restrict__ knn_idx, const float* __restrict__ v_pos,
    int* __restrict__ idx3, float* __restrict__ w3) {
  __shared__ float4 cpos[NM];
  int tid = threadIdx.x, lane = tid & 63, wid = tid >> 6;
  int r = blockIdx.x * 4 + wid;
  int b = (blockIdx.x * 4) / (NK * NN * NG);
  for (int t = tid; t < NM; t += 256) {
    float x = v_pos[((size_t)b * NM + t) * 3 + 0];
    float y = v_pos[((size_t)b * NM + t) * 3 + 1];
    float z = v_pos[((size_t)b * NM + t) * 3 + 2];
    cpos[t] = make_float4(x, y, z, x * x + y * y + z * z);
  }
  __syncthreads();
  int k = r % NK;
  int n = (r / NK) % NN;
  int g = (r / (NK * NN)) % NG;
  int m = knn_idx[((size_t)b * NN + n) * NK + k];
  const float* vc = vcontrib + ((size_t)(g * NB + b) * NM + m) * NC;
  const float* qc = qcontrib + ((size_t)(g * NB + b) * NN + n) * NC;
  float h[6];
  float s = 0.f, s2 = 0.f;
#pragma unroll
  for (int j = 0; j < 6; ++j) {
    int c = j * 64 + lane;
    float x = vc[c] + qc[c] + boff1[c];
    h[j] = x; s += x; s2 += x * x;
  }
  s = wred_sum(s);
  s2 = wred_sum(s2);
  float mean = s * (1.f / NC);
  float var = s2 * (1.f / NC) - mean * mean;
  float inv = 1.f / sqrtf(var + 1e-5f);
  float p0 = 0.f, p1 = 0.f, p2 = 0.f;
#pragma unroll
  for (int j = 0; j < 6; ++j) {
    int c = j * 64 + lane;
    float x = (h[j] - mean) * inv * ln_g[c] + ln_b[c];
    x = 0.5f * x * (1.f + erff(x * 0.70710678118654752f));
    p0 = fmaf(x, Woff2[0 * NC + c], p0);
    p1 = fmaf(x, Woff2[1 * NC + c], p1);
    p2 = fmaf(x, Woff2[2 * NC + c], p2);
  }
  p0 = wred_sum(p0);
  p1 = wred_sum(p1);
  p2 = wred_sum(p2);
  float4 cm = cpos[m];
  float sx = cm.x + tanhf(p0);
  float sy = cm.y + tanhf(p1);
  float sz = cm.z + tanhf(p2);
  float qq2 = sx * sx + sy * sy + sz * sz;
  float d0v = 1e30f, d1v = 1e30f, d2v = 1e30f;
  int i0v = 0x7fffffff, i1v = 0x7fffffff, i2v = 0x7fffffff;
#pragma unroll
  for (int t = 0; t < NM / 64; ++t) {
    int m2 = t * 64 + lane;
    float4 cc = cpos[m2];
    float d = qq2 + cc.w - 2.f * (sx * cc.x + sy * cc.y + sz * cc.z);
    if (d < d2v) {
      d2v = d; i2v = m2;
      if (d2v < d1v) { float td = d1v; d1v = d2v; d2v = td; int ti = i1v; i1v = i2v; i2v = ti; }
      if (d1v < d0v) { float td = d0v; d0v = d1v; d1v = td; int ti = i0v; i0v = i1v; i1v = ti; }
    }
  }
  float rd[3];
  int rm[3];
#pragma unroll
  for (int round = 0; round < 3; ++round) {
    float dh = d0v;
    int mh = i0v;
    wred_argmin(dh, mh);
    rd[round] = dh; rm[round] = mh;
    if (i0v == mh) {
      d0v = d1v; i0v = i1v;
      d1v = d2v; i1v = i2v;
      d2v = 1e30f; i2v = 0x7fffffff;
    }
  }
  if (lane == 0) {
    float e0 = 1.f / (sqrtf(fmaxf(rd[0], 0.f)) + 1e-8f);
    float e1 = 1.f / (sqrtf(fmaxf(rd[1], 0.f)) + 1e-8f);
    float e2 = 1.f / (sqrtf(fmaxf(rd[2], 0.f)) + 1e-8f);
    float sw = e0 + e1 + e2;
    idx3[(size_t)r * 3 + 0] = rm[0]; w3[(size_t)r * 3 + 0] = e0 / sw;
    idx3[(size_t)r * 3 + 1] = rm[1]; w3[(size_t)r * 3 + 1] = e1 / sw;
    idx3[(size_t)r * 3 + 2] = rm[2]; w3[(size_t)r * 3 + 2] = e2 / sw;
  }
}

// one block per (b,n): kf/vf via 6-term gathered sums from bf16 Kc/Vc tables, then attention
__global__ __launch_bounds__(NC) void attn_k(const float* __restrict__ qp,
                                             const ushort* __restrict__ Kc,
                                             const ushort* __restrict__ Vc,
                                             const int* __restrict__ idx3,
                                             const float* __restrict__ w3,
                                             float* __restrict__ attn_out) {
  __shared__ float vfs[NK][NC];
  __shared__ float lgs[NH][NK];
  __shared__ int il[NG][NK][3];
  __shared__ float wl[NG][NK][3];
  int o = threadIdx.x;
  int lane = o & 63, wid = o >> 6;
  int b = blockIdx.x / NN;
  int n = blockIdx.x % NN;
  if (o < NG * NK * 3) {
    int g = o / (NK * 3), k = (o / 3) % NK, j = o % 3;
    size_t rr = (((size_t)(b * NG + g) * NN + n) * NK + k) * 3 + j;
    il[g][k][j] = idx3[rr];
    wl[g][k][j] = w3[rr];
  }
  __syncthreads();
  float qv = qp[((size_t)b * NN + n) * NC + o];
  for (int k = 0; k < NK; ++k) {
    float kf = 0.f, vf = 0.f;
#pragma unroll
    for (int g = 0; g < NG; ++g)
#pragma unroll
      for (int j = 0; j < 3; ++j) {
        int m = il[g][k][j];
        float w = wl[g][k][j];
        size_t base = ((size_t)(g * NB + b) * NM + m) * NC + o;
        kf = fmaf(w, b2f(Kc[base]), kf);
        vf = fmaf(w, b2f(Vc[base]), vf);
      }
    vfs[k][o] = vf;
    float p = wred_sum(qv * kf);
    if (lane == 0) lgs[wid][k] = p * 0.125f;
  }
  __syncthreads();
  float a[NK];
  float mx = -1e30f;
#pragma unroll
  for (int k = 0; k < NK; ++k) { a[k] = lgs[wid][k]; mx = fmaxf(mx, a[k]); }
  float sum = 0.f;
#pragma unroll
  for (int k = 0; k < NK; ++k) { a[k] = expf(a[k] - mx); sum += a[k]; }
  float outv = 0.f;
#pragma unroll
  for (int k = 0; k < NK; ++k) outv = fmaf(a[k] / sum, vfs[k][o], outv);
  attn_out[((size_t)b * NN + n) * NC + o] = outv;
}

extern "C" void kernel_launch(void* const* d_in, const int* in_sizes, int n_in,
                              void* d_out, int out_size, void* d_ws, size_t ws_size,
                              hipStream_t stream) {
  (void)in_sizes; (void)n_in; (void)out_size; (void)ws_size;
  const float* q     = (const float*)d_in[0];
  const float* q_pos = (const float*)d_in[1];
  const float* v     = (const float*)d_in[2];
  const float* v_pos = (const float*)d_in[3];
  const float* Wq    = (const float*)d_in[4];
  const float* Wk    = (const float*)d_in[5];
  const float* Wv    = (const float*)d_in[6];
  const float* Wvoff = (const float*)d_in[7];
  const float* Woff1 = (const float*)d_in[8];
  const float* boff1 = (const float*)d_in[9];
  const float* ln_g  = (const float*)d_in[10];
  const float* ln_b  = (const float*)d_in[11];
  const float* Woff2 = (const float*)d_in[12];
  const float* Wproj = (const float*)d_in[13];
  const float* bproj = (const float*)d_in[14];
  float* out = (float*)d_out;

  char* p = (char*)d_ws;
  auto alloc_f = [&](size_t n) { float* r = (float*)p; p += n * sizeof(float); return r; };
  auto alloc_h = [&](size_t n) { ushort* r = (ushort*)p; p += n * sizeof(ushort); return r; };
  auto alloc_i = [&](size_t n) { int* r = (int*)p; p += n * sizeof(int); return r; };

  float* qp        = alloc_f(QSZ);
  float* qcontrib  = alloc_f((size_t)NG * QSZ);
  float* vcontrib  = alloc_f((size_t)NG * GSZ);
  float* Wt_all    = alloc_f((size_t)WT_ALL_FLOATS);
  float* WcombAll  = alloc_f((size_t)4 * NCNC);
  float* w3        = alloc_f((size_t)NB * NG * NN * NK * 3);
  ushort* KcT      = alloc_h((size_t)NG * GSZ);
  ushort* VcT      = alloc_h((size_t)NG * GSZ);
  int* knn_idx     = alloc_i((size_t)NB * NN * NK);
  int* idx3        = alloc_i((size_t)NB * NG * NN * NK * 3);
  float* attn_out  = vcontrib;  // vcontrib dead after mlp3nn_k; reuse

  transpose_all_k<<<dim3(576, 7), 256, 0, stream>>>(Wq, Woff1, Wk, Wv, Wproj, Wt_all);
  wcomb2_k<<<dim3(NC, 4), 256, 0, stream>>>(Woff1, Wvoff, Wq, WcombAll);
  knn2_k<<<NB * (NN / 4), 256, 0, stream>>>(q_pos, v_pos, knn_idx);

  projall_k<<<dim3(NB * NM / 16, 9), 384, 0, stream>>>(q, v, WcombAll, Wt_all, qp, qcontrib,
                                                       vcontrib, KcT, VcT);

  mlp3nn_k<<<NB * NG * NN * NK / 4, 256, 0, stream>>>(vcontrib, qcontrib, boff1, ln_g, ln_b,
                                                      Woff2, knn_idx, v_pos, idx3, w3);
  attn_k<<<NB * NN, NC, 0, stream>>>(qp, KcT, VcT, idx3, w3, attn_out);
  gemm16_k<<<dim3(NB * NN / 16, 1), 384, 0, stream>>>(attn_out, NC, 0, 0, Wt_all + OFF_WPROJ, 0,
                                                      bproj, out, 0);
}